// Round 3
// baseline (264.841 us; speedup 1.0000x reference)
//
#include <hip/hip_runtime.h>
#include <cstdint>

#define NH 6
#define HD 32
#define NTOK 256
#define CIN 576
#define DIMO 192
#define LOG2E 1.44269504f
#define SHIFT2 37.6f
#define MNEG (-144.269504f)   // -100 * log2(e)

typedef short short8 __attribute__((ext_vector_type(8)));
typedef float f32x4 __attribute__((ext_vector_type(4)));

__device__ __forceinline__ int grp6(int x) { return (x < 48) ? 0 : ((x < 56) ? 1 : 2); }

__device__ __forceinline__ unsigned short f2bf(float f) {
    unsigned int u = __float_as_uint(f);
    u += 0x7fffu + ((u >> 16) & 1u);   // RTNE
    return (unsigned short)(u >> 16);
}

// ---------------- kernel 1: CPB MLP (block per table point) ----------------
__global__ void cpb_kernel(const float* __restrict__ table,
                           const float* __restrict__ w1,
                           const float* __restrict__ b1,
                           const float* __restrict__ w2,
                           float* __restrict__ bv) {
    __shared__ float hid[512];
    int p = blockIdx.x;                 // 0..960
    float t0 = table[2 * p], t1 = table[2 * p + 1];
    int t = threadIdx.x;                // 256 threads
    for (int j = t; j < 512; j += 256) {
        float hv = fmaf(t0, w1[2 * j], fmaf(t1, w1[2 * j + 1], b1[j]));
        hid[j] = fmaxf(hv, 0.f);
    }
    __syncthreads();
    if (t < 192) {
        int h = t >> 5, l = t & 31;
        const float* w2h = w2 + h * 512;
        float acc = 0.f;
        for (int j = l; j < 512; j += 32) acc = fmaf(hid[j], w2h[j], acc);
        acc += __shfl_xor(acc, 1, 32);
        acc += __shfl_xor(acc, 2, 32);
        acc += __shfl_xor(acc, 4, 32);
        acc += __shfl_xor(acc, 8, 32);
        acc += __shfl_xor(acc, 16, 32);
        if (l == 0) bv[h * 961 + p] = (16.f / (1.f + __expf(-acc))) * LOG2E;
    }
}

// ---------------- kernel 2: MFMA attention ----------------
// block = one (window, head), 512 threads = 8 waves; wave w owns q-rows [w*32, w*32+32)
__global__ __launch_bounds__(512, 4) void attn_kernel(
    const float* __restrict__ qkv,
    const float* __restrict__ logit_scale,
    const float* __restrict__ bv,
    float* __restrict__ out)
{
    __shared__ __align__(16) short Kb[NTOK * HD];   // 16 KB   K bf16 normalized
    __shared__ __align__(16) short Vt[HD * 264];    // 16.9 KB V^T, stride 264
    __shared__ __align__(16) short QP[NTOK * HD];   // 16 KB   Q staging, then per-wave P
    __shared__ __align__(16) float Bf[31 * 256];    // 31 KB   bias in C-fragment layout, SHIFT2 folded

    const int t = threadIdx.x;
    const int h = blockIdx.x % NH;
    const int win = blockIdx.x / NH;
    const int b = win >> 4, wl = win & 15, wh = wl >> 2, ww = wl & 3;

    const float scale2 = __expf(fminf(logit_scale[h], 4.6051702f)) * LOG2E;

    // ---- build fragment-layout bias table: Bf[d15*256 + lane*4 + reg]
    //      value = bias[(d15)*31 + (quad*4+reg - l15 + 15)] - SHIFT2
    {
        const float* bvh = bv + h * 961;
        for (int idx = t; idx < 31 * 256; idx += 512) {
            int d15 = idx >> 8, ln = (idx >> 2) & 63, rg = idx & 3;
            int col = ((ln >> 4) * 4 + rg) - (ln & 15) + 15;   // 0..30
            Bf[idx] = bvh[d15 * 31 + col] - SHIFT2;
        }
    }

    // ---- staging: threads 0..255 do Q,K; 256..511 do V^T
    {
        int n = (t < 256) ? t : (t - 256);
        int i = n >> 4, j = n & 15;
        int rr = wh * 16 + i, cc = ww * 16 + j;
        int r = (rr + 8) & 63, c = (cc + 8) & 63;
        const float* base = qkv + ((long)(b * 4096 + r * 64 + c)) * CIN + h * HD;
        if (t < 256) {
            float qv[32], kv[32];
            const float4* qp = (const float4*)base;
            const float4* kp = (const float4*)(base + DIMO);
#pragma unroll
            for (int w = 0; w < 8; ++w) {
                float4 x = qp[w];
                qv[4 * w + 0] = x.x; qv[4 * w + 1] = x.y; qv[4 * w + 2] = x.z; qv[4 * w + 3] = x.w;
            }
#pragma unroll
            for (int w = 0; w < 8; ++w) {
                float4 x = kp[w];
                kv[4 * w + 0] = x.x; kv[4 * w + 1] = x.y; kv[4 * w + 2] = x.z; kv[4 * w + 3] = x.w;
            }
            float sq = 0.f, sk = 0.f;
#pragma unroll
            for (int d = 0; d < 32; ++d) { sq = fmaf(qv[d], qv[d], sq); sk = fmaf(kv[d], kv[d], sk); }
            float qs = scale2 / fmaxf(sqrtf(sq), 1e-12f);
            float ks = 1.f / fmaxf(sqrtf(sk), 1e-12f);
#pragma unroll
            for (int w = 0; w < 4; ++w) {
                short8 qc, kc;
#pragma unroll
                for (int e = 0; e < 8; ++e) {
                    qc[e] = (short)f2bf(qv[8 * w + e] * qs);
                    kc[e] = (short)f2bf(kv[8 * w + e] * ks);
                }
                *(short8*)&QP[n * 32 + 8 * w] = qc;
                *(short8*)&Kb[n * 32 + 8 * w] = kc;
            }
        } else {
            float vv[32];
            const float4* vp = (const float4*)(base + 2 * DIMO);
#pragma unroll
            for (int w = 0; w < 8; ++w) {
                float4 x = vp[w];
                vv[4 * w + 0] = x.x; vv[4 * w + 1] = x.y; vv[4 * w + 2] = x.z; vv[4 * w + 3] = x.w;
            }
#pragma unroll
            for (int d = 0; d < 32; ++d) Vt[d * 264 + n] = (short)f2bf(vv[d]);
        }
    }
    __syncthreads();

    // ---- per-wave MFMA flash loop
    const int wv = t >> 6, lane = t & 63, quad = lane >> 4, l15 = lane & 15;
    short* Pw = QP + wv * 1024;   // aliases this wave's own Q rows (fully consumed below)

    int trg[2];
    short8 aQ[2];
#pragma unroll
    for (int tl = 0; tl < 2; ++tl) {
        trg[tl] = wv * 2 + tl;
        aQ[tl] = *(const short8*)&QP[(trg[tl] * 16 + l15) * 32 + quad * 8];
    }
    int gqi[2];
#pragma unroll
    for (int tl = 0; tl < 2; ++tl) gqi[tl] = grp6(wh * 16 + trg[tl]);
    int gqj[4];
#pragma unroll
    for (int reg = 0; reg < 4; ++reg) gqj[reg] = grp6(ww * 16 + quad * 4 + reg);
    const int gmj = grp6(ww * 16 + l15);

    f32x4 O[2][2], Osum[2];
#pragma unroll
    for (int tl = 0; tl < 2; ++tl) {
#pragma unroll
        for (int dtk = 0; dtk < 2; ++dtk) O[tl][dtk] = (f32x4){0.f, 0.f, 0.f, 0.f};
        Osum[tl] = (f32x4){0.f, 0.f, 0.f, 0.f};
    }

    short8 bOne;
#pragma unroll
    for (int e = 0; e < 8; ++e) bOne[e] = (short)0x3F80;   // 1.0 bf16

    for (int c = 0; c < 8; ++c) {
        short8 bK[2];
        int gmi[2], ctg[2];
#pragma unroll
        for (int ct = 0; ct < 2; ++ct) {
            ctg[ct] = c * 2 + ct;
            bK[ct] = *(const short8*)&Kb[(ctg[ct] * 16 + l15) * 32 + quad * 8];
            gmi[ct] = grp6(wh * 16 + ctg[ct]);
        }
        // S = Q*K^T + bias (bias+(-SHIFT2) rides the MFMA C operand)
        f32x4 S[2][2];
#pragma unroll
        for (int tl = 0; tl < 2; ++tl)
#pragma unroll
            for (int ct = 0; ct < 2; ++ct) {
                f32x4 Bfr = *(const f32x4*)&Bf[((trg[tl] - ctg[ct] + 15) << 8) + (lane << 2)];
                S[tl][ct] = __builtin_amdgcn_mfma_f32_16x16x32_bf16(aQ[tl], bK[ct], Bfr, 0, 0, 0);
            }
        // epilogue: mask + exp2, pack to bf16 P
#pragma unroll
        for (int tl = 0; tl < 2; ++tl) {
#pragma unroll
            for (int ct = 0; ct < 2; ++ct) {
                bool mi = (gqi[tl] == gmi[ct]);
#pragma unroll
                for (int reg = 0; reg < 4; ++reg) {
                    float mterm = (mi && (gqj[reg] == gmj)) ? 0.f : MNEG;
                    float e = __builtin_amdgcn_exp2f(S[tl][ct][reg] + mterm);
                    unsigned int u = __float_as_uint(e) + 0x8000u;   // round-half-up bf16
                    Pw[(tl * 16 + quad * 4 + reg) * 32 + ct * 16 + l15] = (short)(u >> 16);
                }
            }
        }
        // PV: O += P*V ; Osum += P*1 (row sums, consistent with truncated P)
        short8 aP[2], bV[2];
#pragma unroll
        for (int tl = 0; tl < 2; ++tl)
            aP[tl] = *(const short8*)&Pw[(tl * 16 + l15) * 32 + quad * 8];
#pragma unroll
        for (int dtk = 0; dtk < 2; ++dtk)
            bV[dtk] = *(const short8*)&Vt[(dtk * 16 + l15) * 264 + c * 32 + quad * 8];
#pragma unroll
        for (int tl = 0; tl < 2; ++tl) {
#pragma unroll
            for (int dtk = 0; dtk < 2; ++dtk)
                O[tl][dtk] = __builtin_amdgcn_mfma_f32_16x16x32_bf16(aP[tl], bV[dtk], O[tl][dtk], 0, 0, 0);
            Osum[tl] = __builtin_amdgcn_mfma_f32_16x16x32_bf16(aP[tl], bOne, Osum[tl], 0, 0, 0);
        }
    }

    // store (window-reverse + unshift folded into pixel calc)
    const long pixb = (long)b * 4096;
#pragma unroll
    for (int tl = 0; tl < 2; ++tl) {
        int r = (wh * 16 + trg[tl] + 8) & 63;
#pragma unroll
        for (int reg = 0; reg < 4; ++reg) {
            int cpix = (ww * 16 + quad * 4 + reg + 8) & 63;
            float* op = out + (pixb + r * 64 + cpix) * DIMO + h * HD + l15;
            float inv = 1.f / Osum[tl][reg];
            op[0]  = O[tl][0][reg] * inv;
            op[16] = O[tl][1][reg] * inv;
        }
    }
}

extern "C" void kernel_launch(void* const* d_in, const int* in_sizes, int n_in,
                              void* d_out, int out_size, void* d_ws, size_t ws_size,
                              hipStream_t stream) {
    const float* qkv         = (const float*)d_in[0];
    const float* table       = (const float*)d_in[1];
    // d_in[2] = mask   : recomputed from window-region groups
    const float* logit_scale = (const float*)d_in[3];
    const float* w1          = (const float*)d_in[4];
    const float* b1          = (const float*)d_in[5];
    const float* w2          = (const float*)d_in[6];
    // d_in[7] = index  : recomputed from relative coords
    float* out = (float*)d_out;
    float* bv  = (float*)d_ws;   // 6*961 floats

    cpb_kernel<<<961, 256, 0, stream>>>(table, w1, b1, w2, bv);
    attn_kernel<<<256 * NH, 512, 0, stream>>>(qkv, logit_scale, bv, out);
}